// Round 7
// baseline (26.095 us; speedup 1.0000x reference)
//
#include <hip/hip_runtime.h>

// MedianFilter2D: 3x3 median, reflect pad, [16,3,512,512] f32.
// Per-row horizontal sorted triple (hmin,hmed,hmax); median9 =
// med3( max3(hmin x3), med3(hmed x3), min3(hmax x3) ).
// R6: one WAVE per full 512-col row (lane i owns cols 8i..8i+7, 2x dwordx4
// per row). All column halos are register/shuffle — zero divergent edge
// loads, so no per-row vmcnt(0) drain (R3-R5's hidden serializer).
// Each wave: R=8 consecutive rows, rolling triples, depth-2 load pipeline.

constexpr int Wd = 512;
constexpr int Hd = 512;
constexpr int R  = 8;   // output rows per wave

typedef float f32x4 __attribute__((ext_vector_type(4)));

__device__ __forceinline__ float med3f(float a, float b, float c) {
    return __builtin_amdgcn_fmed3f(a, b, c);
}
__device__ __forceinline__ float min3f(float a, float b, float c) {
    return fminf(fminf(a, b), c);   // v_min3_f32
}
__device__ __forceinline__ float max3f(float a, float b, float c) {
    return fmaxf(fmaxf(a, b), c);   // v_max3_f32
}

struct Raw  { f32x4 a, b; };                 // cols 8i..8i+3, 8i+4..8i+7
struct Trip { float mn[8], md[8], mx[8]; };  // per-col sorted triples

__global__ __launch_bounds__(256) void MedianFilter2D_68745246540291_kernel(
    const float* __restrict__ in, float* __restrict__ out, int nwaves) {
    int wid = (blockIdx.x * blockDim.x + threadIdx.x) >> 6;
    if (wid >= nwaves) return;
    int lane = threadIdx.x & 63;

    int rt = wid & (Hd / R - 1);       // row tile within plane
    int r0 = rt * R;
    long plane = (long)(wid >> 6);     // Hd/R = 64 tiles per plane

    const float* p = in  + plane * (long)(Hd * Wd);
    float*       q = out + plane * (long)(Hd * Wd);
    int c0 = lane << 3;                // first of this lane's 8 columns

    auto loadraw = [&](int g) -> Raw {
        int h = (g < 0) ? 1 : ((g > Hd - 1) ? Hd - 2 : g);   // reflect rows
        const float* rp = p + (long)h * Wd + c0;
        Raw r;
        r.a = *reinterpret_cast<const f32x4*>(rp);
        r.b = *reinterpret_cast<const f32x4*>(rp + 4);
        return r;
    };
    auto mktrip = [&](Raw r) -> Trip {
        // v[0..9] = cols c0-1 .. c0+8 (halos via shuffle / in-register reflect)
        float vl = __shfl_up(r.b.w, 1);          // lane-1's col c0-1
        float vr = __shfl_down(r.a.x, 1);        // lane+1's col c0+8
        if (lane == 0)  vl = r.a.y;              // col -1  -> col 1
        if (lane == 63) vr = r.b.z;              // col 512 -> col 510
        float v[10] = { vl, r.a.x, r.a.y, r.a.z, r.a.w,
                            r.b.x, r.b.y, r.b.z, r.b.w, vr };
        Trip t;
#pragma unroll
        for (int j = 0; j < 8; ++j) {
            t.mn[j] = min3f(v[j], v[j + 1], v[j + 2]);
            t.md[j] = med3f(v[j], v[j + 1], v[j + 2]);
            t.mx[j] = max3f(v[j], v[j + 1], v[j + 2]);
        }
        return t;
    };

    // prologue: rows r0-1, r0 into triples; row r0+1 raw in flight
    Raw rawC = loadraw(r0 - 1);
    Raw rawD = loadraw(r0);
    Trip t0 = mktrip(rawC);
    rawC = loadraw(r0 + 1);
    Trip t1 = mktrip(rawD);

#pragma unroll
    for (int i = 0; i < R; ++i) {
        if (i < R - 1) rawD = loadraw(r0 + i + 2);   // depth-2 pipeline
        Trip t2 = mktrip(rawC);
        f32x4 oa, ob;
#pragma unroll
        for (int j = 0; j < 8; ++j) {
            float lo = max3f(t0.mn[j], t1.mn[j], t2.mn[j]);
            float mi = med3f(t0.md[j], t1.md[j], t2.md[j]);
            float hi = min3f(t0.mx[j], t1.mx[j], t2.mx[j]);
            ((j < 4) ? oa : ob)[j & 3] = med3f(lo, mi, hi);
        }
        float* wp = q + (long)(r0 + i) * Wd + c0;
        __builtin_nontemporal_store(oa, reinterpret_cast<f32x4*>(wp));
        __builtin_nontemporal_store(ob, reinterpret_cast<f32x4*>(wp + 4));
        t0 = t1;
        t1 = t2;
        rawC = rawD;
    }
}

extern "C" void kernel_launch(void* const* d_in, const int* in_sizes, int n_in,
                              void* d_out, int out_size, void* d_ws, size_t ws_size,
                              hipStream_t stream) {
    const float* in = (const float*)d_in[0];
    float* out = (float*)d_out;
    int nwaves = out_size / (Wd * R);          // one wave per R-row strip
    int block = 256;
    int grid = (nwaves * 64 + block - 1) / block;   // 768 blocks
    MedianFilter2D_68745246540291_kernel<<<grid, block, 0, stream>>>(in, out, nwaves);
}

// Round 8
// 21.453 us; speedup vs baseline: 1.2164x; 1.2164x over previous
//
#include <hip/hip_runtime.h>

// MedianFilter2D: 3x3 median, reflect pad, [16,3,512,512] f32.
// Per-row horizontal sorted triple (hmin,hmed,hmax); median9 =
// med3( max3(hmin x3), med3(hmed x3), min3(hmax x3) ).
// R7: concurrency fix. R=8 rows/thread (24 waves/CU, 2x previous) and a
// depth-3 rolling load pipeline: each row's loads (main dwordx4 AND the
// 1-lane edge loads, now issued at load time) stay in flight ~3 iterations
// (~450cy) before consumption. All indices static (fully unrolled).

constexpr int Wd = 512;
constexpr int Hd = 512;
constexpr int R  = 8;   // output rows per thread

typedef float f32x4 __attribute__((ext_vector_type(4)));

__device__ __forceinline__ float med3f(float a, float b, float c) {
    return __builtin_amdgcn_fmed3f(a, b, c);
}
__device__ __forceinline__ float min3f(float a, float b, float c) {
    return fminf(fminf(a, b), c);   // v_min3_f32
}
__device__ __forceinline__ float max3f(float a, float b, float c) {
    return fmaxf(fmaxf(a, b), c);   // v_max3_f32
}

struct Raw  { f32x4 c; float e0, e5; };      // main 4 cols + 2 edge scalars
struct Trip { float mn[4], md[4], mx[4]; };

__global__ __launch_bounds__(256, 4) void MedianFilter2D_68745246540291_kernel(
    const float* __restrict__ in, float* __restrict__ out, int total) {
    int idx = blockIdx.x * blockDim.x + threadIdx.x;
    if (idx >= total) return;

    int lane = threadIdx.x & 63;
    int cg   = idx & 127;          // column group (4 cols each)
    int w4   = cg << 2;
    int rt   = (idx >> 7) & (Hd / R - 1);
    int r0   = rt * R;
    long plane = (long)(idx >> 13);

    const float* p = in  + plane * (long)(Hd * Wd);
    float*       q = out + plane * (long)(Hd * Wd);

    // issue ALL of a row's memory ops here (pipelined D rows ahead)
    auto loadraw = [&](int g) -> Raw {
        int h = (g < 0) ? 1 : ((g > Hd - 1) ? Hd - 2 : g);   // reflect rows
        const float* rp = p + (long)h * Wd;
        Raw r;
        r.c  = *reinterpret_cast<const f32x4*>(rp + w4);
        r.e0 = (lane == 0  && cg != 0)   ? rp[w4 - 1] : 0.f; // 1-lane loads
        r.e5 = (lane == 63 && cg != 127) ? rp[w4 + 4] : 0.f;
        return r;
    };
    // pure register/shuffle/VALU — no memory ops at consume time
    auto mktrip = [&](Raw r) -> Trip {
        float v0 = __shfl_up(r.c.w, 1);
        float v5 = __shfl_down(r.c.x, 1);
        if (lane == 0)  v0 = (cg == 0)   ? r.c.y : r.e0;
        if (lane == 63) v5 = (cg == 127) ? r.c.z : r.e5;
        float v[6] = { v0, r.c.x, r.c.y, r.c.z, r.c.w, v5 };
        Trip t;
#pragma unroll
        for (int j = 0; j < 4; ++j) {
            t.mn[j] = min3f(v[j], v[j + 1], v[j + 2]);
            t.md[j] = med3f(v[j], v[j + 1], v[j + 2]);
            t.mx[j] = max3f(v[j], v[j + 1], v[j + 2]);
        }
        return t;
    };

    // depth-3 pipeline: slots hold rows (about-to-consume, +1, +2)
    Raw raw[3];
#pragma unroll
    for (int k = 0; k < 3; ++k) raw[k] = loadraw(r0 - 1 + k);

    Trip t[3];
    t[0] = mktrip(raw[0]);  raw[0] = loadraw(r0 + 2);
    t[1] = mktrip(raw[1]);  raw[1] = loadraw(r0 + 3);

#pragma unroll
    for (int i = 0; i < R; ++i) {
        const int s = (i + 2) % 3;
        t[s] = mktrip(raw[s]);                       // row r0+i+1
        if (i <= R - 4) raw[s] = loadraw(r0 + i + 4);// keep 3 rows in flight
        const Trip& a = t[i % 3];
        const Trip& b = t[(i + 1) % 3];
        const Trip& c = t[s];
        f32x4 o;
#pragma unroll
        for (int j = 0; j < 4; ++j) {
            float lo = max3f(a.mn[j], b.mn[j], c.mn[j]);
            float mi = med3f(a.md[j], b.md[j], c.md[j]);
            float hi = min3f(a.mx[j], b.mx[j], c.mx[j]);
            o[j] = med3f(lo, mi, hi);
        }
        __builtin_nontemporal_store(o, reinterpret_cast<f32x4*>(
            q + (long)(r0 + i) * Wd + w4));
    }
}

extern "C" void kernel_launch(void* const* d_in, const int* in_sizes, int n_in,
                              void* d_out, int out_size, void* d_ws, size_t ws_size,
                              hipStream_t stream) {
    const float* in = (const float*)d_in[0];
    float* out = (float*)d_out;
    int total = out_size / (4 * R);            // threads: 4 cols x R rows each
    int block = 256;
    int grid = (total + block - 1) / block;    // 1536 blocks, 24 waves/CU
    MedianFilter2D_68745246540291_kernel<<<grid, block, 0, stream>>>(in, out, total);
}